// Round 1
// baseline (840.830 us; speedup 1.0000x reference)
//
#include <hip/hip_runtime.h>

// Problem shapes (fixed by the reference):
//   kv_cache:     (2L, B, H, S, D) = (4, 8, 8, 4096, 128) fp32  -> 512 MiB
//   new_kv:       (L, 2, B, H, 1, D) = (2, 2, 8, 8, 1, 128) fp32 -> 128 KiB
//   position_ids: (B, 1) int -> 8 elems
//   out:          same shape as kv_cache, = kv_cache with row pos[b] of each
//                 (c, b, h) slice replaced by new_kv[c, b, h, :]
// where c = 2*l + kv_type runs 0..3 and indexes identically into both the
// leading dim of kv_cache/out and the flattened (L,2) dims of new_kv.

#define LL 2
#define BB 8
#define HH 8
#define SS 4096
#define DD 128

// 2L*B*H*D = 32768 elements to scatter. One thread per float4 -> 8192 threads.
__global__ void kv_scatter_kernel(const float4* __restrict__ new_kv,
                                  const int* __restrict__ pos_ids,
                                  float* __restrict__ out) {
    int tid = blockIdx.x * blockDim.x + threadIdx.x;   // 0 .. 8191
    // Each tid covers 4 consecutive floats of new_kv (flat).
    int d4   = tid & (DD / 4 - 1);        // 0..31  (float4 index within D)
    int rest = tid >> 5;
    int h    = rest & (HH - 1);
    rest >>= 3;
    int b    = rest & (BB - 1);
    int c    = rest >> 3;                  // 0..3
    int pos  = pos_ids[b];

    float4 v = new_kv[tid];
    size_t row = ((((size_t)c * BB + b) * HH + h) * SS + (size_t)pos);
    float4* dst = (float4*)(out + row * DD) + d4;
    *dst = v;
}

extern "C" void kernel_launch(void* const* d_in, const int* in_sizes, int n_in,
                              void* d_out, int out_size, void* d_ws, size_t ws_size,
                              hipStream_t stream) {
    const float* kv_cache = (const float*)d_in[0];
    const float* new_kv   = (const float*)d_in[1];
    const int*   pos_ids  = (const int*)d_in[2];
    float*       out      = (float*)d_out;

    // Bulk copy of the whole cache to the output (512 MiB).
    size_t bytes = (size_t)out_size * sizeof(float);
    hipMemcpyAsync(d_out, (const void*)kv_cache, bytes,
                   hipMemcpyDeviceToDevice, stream);

    // Overwrite the 256 updated rows (ordered after the copy on `stream`).
    const int total_f4 = LL * 2 * BB * HH * (DD / 4);   // 8192
    const int block = 256;
    kv_scatter_kernel<<<total_f4 / block, block, 0, stream>>>(
        (const float4*)new_kv, pos_ids, out);
}